// Round 1
// baseline (703.389 us; speedup 1.0000x reference)
//
#include <hip/hip_runtime.h>
#include <cmath>

// ---- problem constants ----
#define WD 128
#define HT 128
#define HW 16384            // H*W
#define NB 4
#define NA 9
#define NPB (NA*HW)         // anchors per batch = 147456
#define TOPN 4000
#define POSTN 1000
#define CANDCAP 8192
#define SORTN 8192
#define MROWS 4096          // padded rows for mask / topk buffers
#define NTILE 63            // ceil(4000/64)

typedef unsigned long long u64;
typedef unsigned int u32;

struct Anchors { float v[36]; };

// ---------------- host: replicate numpy _generate_anchors exactly ----------------
static void gen_anchors(float* out) {
    double base[4] = {0.0, 0.0, 15.0, 15.0};
    const double ratios[3] = {0.5, 1.0, 2.0};
    const double scales[3] = {8.0, 16.0, 32.0};
    double w = base[2] - base[0] + 1.0;
    double h = base[3] - base[1] + 1.0;
    double xc = base[0] + 0.5 * (w - 1.0);
    double yc = base[1] + 0.5 * (h - 1.0);
    double size = w * h;
    double ra[3][4];
    for (int r = 0; r < 3; ++r) {
        double ws = nearbyint(sqrt(size / ratios[r]));   // np.round = half-even
        double hs = nearbyint(ws * ratios[r]);
        ra[r][0] = xc - 0.5 * (ws - 1.0);
        ra[r][1] = yc - 0.5 * (hs - 1.0);
        ra[r][2] = xc + 0.5 * (ws - 1.0);
        ra[r][3] = yc + 0.5 * (hs - 1.0);
    }
    int k = 0;
    for (int r = 0; r < 3; ++r) {
        double w2 = ra[r][2] - ra[r][0] + 1.0;
        double h2 = ra[r][3] - ra[r][1] + 1.0;
        double x2c = ra[r][0] + 0.5 * (w2 - 1.0);
        double y2c = ra[r][1] + 0.5 * (h2 - 1.0);
        for (int s = 0; s < 3; ++s) {
            double ws = w2 * scales[s], hs = h2 * scales[s];
            out[k*4+0] = (float)(x2c - 0.5 * (ws - 1.0));
            out[k*4+1] = (float)(y2c - 0.5 * (hs - 1.0));
            out[k*4+2] = (float)(x2c + 0.5 * (ws - 1.0));
            out[k*4+3] = (float)(y2c + 0.5 * (hs - 1.0));
            ++k;
        }
    }
}

__device__ __forceinline__ u32 sortable_key(float sc) {
    u32 sb = __float_as_uint(sc);
    return sb ^ ((sb & 0x80000000u) ? 0xFFFFFFFFu : 0x80000000u);
}

// ---------------- kernel 1: decode proposals + filtered scores + 16-bit histogram ----------------
__global__ void k_props(const float* __restrict__ scores,
                        const float* __restrict__ deltas,
                        const float* __restrict__ im_info,
                        const float* __restrict__ valid_range,
                        Anchors A,
                        float4* __restrict__ props,
                        float* __restrict__ fscores,
                        u32* __restrict__ hist)
{
#pragma clang fp contract(off)
    int n = blockIdx.x * blockDim.x + threadIdx.x;
    if (n >= NB*NPB) return;
    int b = n / NPB;
    int r = n - b*NPB;
    int a = r / HW;
    int p = r - a*HW;
    int hh = p >> 7;        // / W
    int ww = p & 127;       // % W

    float sx = (float)(ww * 16);
    float sy = (float)(hh * 16);
    float ax1 = A.v[a*4+0] + sx;
    float ay1 = A.v[a*4+1] + sy;
    float ax2 = A.v[a*4+2] + sx;
    float ay2 = A.v[a*4+3] + sy;

    const float* dbase = deltas + ((size_t)(b*36 + a*4))*HW + p;
    float dx = dbase[0];
    float dy = dbase[HW];
    float dw = dbase[2*HW];
    float dh = dbase[3*HW];
    float sc = scores[((size_t)(b*18 + 9 + a))*HW + p];

    float aw = ax2 - ax1 + 1.0f;
    float ah = ay2 - ay1 + 1.0f;
    float cx = ax1 + 0.5f*aw;
    float cy = ay1 + 0.5f*ah;
    float pcx = dx*aw + cx;
    float pcy = dy*ah + cy;
    float ew = (float)exp((double)dw);   // correctly-rounded f32 exp
    float eh = (float)exp((double)dh);
    float pw = ew * aw;
    float ph = eh * ah;
    float x1 = pcx - 0.5f*pw;
    float y1 = pcy - 0.5f*ph;
    float x2 = pcx + 0.5f*pw;
    float y2 = pcy + 0.5f*ph;

    float hmax = im_info[b*3+0] - 1.0f;
    float wmax = im_info[b*3+1] - 1.0f;
    x1 = fmaxf(x1, 0.0f); y1 = fmaxf(y1, 0.0f);
    x2 = fmaxf(x2, 0.0f); y2 = fmaxf(y2, 0.0f);
    x1 = fminf(x1, wmax); y1 = fminf(y1, hmax);
    x2 = fminf(x2, wmax); y2 = fminf(y2, hmax);

    float width  = x2 - x1;
    float height = y2 - y1;
    float area = width * height;
    float v0 = valid_range[b*2+0], v1 = valid_range[b*2+1];
    float mina = v0*v0, maxa = v1*v1;
    if (area < mina || area > maxa) sc = -1.0f;

    props[n] = make_float4(x1, y1, x2, y2);
    fscores[n] = sc;
    u32 key = sortable_key(sc);
    atomicAdd(&hist[(size_t)b*65536 + (key >> 16)], 1u);
}

// ---------------- kernel 2: find per-batch 16-bit threshold bin ----------------
__global__ void k_findthresh(const u32* __restrict__ hist, int* __restrict__ thresh)
{
    __shared__ u32 csum[256];
    int b = blockIdx.x, tid = threadIdx.x;
    const u32* h = hist + (size_t)b*65536;
    u32 s = 0;
    int base = tid * 256;
    for (int i = 0; i < 256; ++i) s += h[base + i];
    csum[tid] = s;
    __syncthreads();
    if (tid == 0) {
        u32 acc = 0; int c = 255;
        for (; c >= 0; --c) {
            if (acc + csum[c] >= TOPN) break;
            acc += csum[c];
        }
        int bin = c*256 + 255;
        for (; bin >= c*256; --bin) {
            u32 hb = h[bin];
            if (acc + hb >= TOPN) break;
            acc += hb;
        }
        thresh[b] = bin;
    }
}

// ---------------- kernel 3: compact candidates (bin >= thresh) ----------------
__global__ void k_compact(const float* __restrict__ fscores,
                          const int* __restrict__ thresh,
                          u64* __restrict__ cand, u32* __restrict__ ccnt)
{
    int n = blockIdx.x * blockDim.x + threadIdx.x;
    if (n >= NB*NPB) return;
    int b = n / NPB;
    int r = n - b*NPB;
    int a = r / HW;
    int p = r - a*HW;
    float sc = fscores[n];
    u32 key = sortable_key(sc);
    if ((int)(key >> 16) >= thresh[b]) {
        u32 pos = atomicAdd(&ccnt[b], 1u);
        if (pos < CANDCAP) {
            u32 t = (u32)(p*NA + a);               // reference flat index
            cand[(size_t)b*CANDCAP + pos] = ((u64)key << 32) | (u32)(~t);
        }
    }
}

// ---------------- kernel 4: bitonic sort 8192 u64 keys, gather top-4000 boxes ----------------
__global__ void k_sort(const u64* __restrict__ cand, const u32* __restrict__ ccnt,
                       const float4* __restrict__ props, float4* __restrict__ topk)
{
    extern __shared__ u64 sk[];
    int b = blockIdx.x, tid = threadIdx.x;
    u32 cnt = ccnt[b]; if (cnt > CANDCAP) cnt = CANDCAP;
    for (int i = tid; i < SORTN; i += 1024)
        sk[i] = (i < (int)cnt) ? cand[(size_t)b*CANDCAP + i] : 0ULL;
    __syncthreads();
    for (int k = 2; k <= SORTN; k <<= 1) {
        for (int j = k >> 1; j > 0; j >>= 1) {
            for (int e = tid; e < SORTN; e += 1024) {
                int ixj = e ^ j;
                if (ixj > e) {
                    u64 x = sk[e], y = sk[ixj];
                    bool desc = ((e & k) == 0);
                    if (desc ? (x < y) : (x > y)) { sk[e] = y; sk[ixj] = x; }
                }
            }
            __syncthreads();
        }
    }
    for (int r = tid; r < TOPN; r += 1024) {
        u64 key = sk[r];
        float4 bx;
        if (key != 0ULL) {
            u32 t = ~((u32)key);
            int a = (int)(t % 9u);
            int p = (int)(t / 9u);
            bx = props[(size_t)b*NPB + (size_t)a*HW + p];
        } else {
            bx = make_float4(0.f, 0.f, 0.f, 0.f);
        }
        topk[(size_t)b*MROWS + r] = bx;
    }
}

// ---------------- kernel 5: suppression-mask tiles (sup_mat & (j>i)) ----------------
__global__ void k_mask(const float4* __restrict__ topk, u64* __restrict__ masks)
{
#pragma clang fp contract(off)
    int tj = blockIdx.x, ti = blockIdx.y, b = blockIdx.z;
    int r = threadIdx.x;           // 0..63
    int i = ti*64 + r;
    __shared__ float4 cb[64];
    __shared__ float  ca[64];
    u64 word = 0;
    if (tj >= ti) {
        int jj = tj*64 + r;
        float4 cbox = (jj < TOPN) ? topk[(size_t)b*MROWS + jj] : make_float4(0,0,0,0);
        cb[r] = cbox;
        ca[r] = (cbox.z - cbox.x + 1.0f) * (cbox.w - cbox.y + 1.0f);
        __syncthreads();
        if (i < TOPN) {
            float4 rb = topk[(size_t)b*MROWS + i];
            float rarea = (rb.z - rb.x + 1.0f) * (rb.w - rb.y + 1.0f);
            for (int q = 0; q < 64; ++q) {
                float4 cc = cb[q];
                float iw = fminf(rb.z, cc.z) - fmaxf(rb.x, cc.x) + 1.0f;
                float ih = fminf(rb.w, cc.w) - fmaxf(rb.y, cc.y) + 1.0f;
                iw = fmaxf(iw, 0.0f); ih = fmaxf(ih, 0.0f);
                float inter = iw * ih;
                float uni = (rarea + ca[q]) - inter;
                float iou = inter / uni;       // IEEE fp32 division, like numpy
                if (iou > 0.7f) word |= (1ULL << q);
            }
            int nvalid = TOPN - tj*64;
            if (nvalid < 64) word &= ((1ULL << nvalid) - 1ULL);
            if (ti == tj) {
                u64 cm = (r == 63) ? ~0ULL : ((1ULL << (r + 1)) - 1ULL);
                word &= ~cm;                   // enforce j > i
            }
        }
    }
    if (i < TOPN) masks[((size_t)b*MROWS + i)*64 + tj] = word;
}

// ---------------- kernel 6: fill output with [b,0,0,0,0] ----------------
__global__ void k_fill(float* __restrict__ out)
{
    int e = blockIdx.x * blockDim.x + threadIdx.x;
    if (e >= NB*POSTN*5) return;
    int within = e % 5;
    int b = e / (POSTN*5);
    out[e] = (within == 0) ? (float)b : 0.0f;
}

// ---------------- kernel 7: sequential greedy scan (1 wave per batch) + output ----------------
__global__ void k_nms(const u64* __restrict__ masks,
                      const float4* __restrict__ topk,
                      float* __restrict__ out)
{
    int b = blockIdx.x;
    int lane = threadIdx.x;        // 0..63; lane owns removed-word lane
    const u64* base = masks + (size_t)b*MROWS*64 + lane;
    u64 rem = 0;
    u64 buf[8];
#pragma unroll
    for (int u = 0; u < 8; ++u) buf[u] = base[(size_t)u*64];
    for (int i0 = 0; i0 < TOPN; i0 += 8) {
#pragma unroll
        for (int u = 0; u < 8; ++u) {
            int i = i0 + u;
            u32 rlo = (u32)rem, rhi = (u32)(rem >> 32);
            u32 half = (i & 32) ? rhi : rlo;
            u32 w32 = (u32)__builtin_amdgcn_readlane((int)half, i >> 6);
            bool sup = (w32 >> (i & 31)) & 1u;
            u64 roww = (lane < 63) ? buf[u] : 0ULL;
            if (!sup) rem |= roww;
            buf[u] = base[(size_t)(i + 8) * 64];   // prefetch 8 rows ahead
        }
    }
    // enumerate kept rows in ascending order
    u64 valid = (lane < 62) ? ~0ULL : (lane == 62 ? 0xFFFFFFFFULL : 0ULL);
    u64 keepw = (~rem) & valid;
    int cnt = __popcll(keepw);
    int pre = cnt;
    for (int d = 1; d < 64; d <<= 1) {
        int t = __shfl_up(pre, d);
        if (lane >= d) pre += t;
    }
    int excl = pre - cnt;
    u64 wv = keepw; int rk = excl;
    while (wv) {
        int bpos = __ffsll((unsigned long long)wv) - 1;
        wv &= wv - 1;
        if (rk < POSTN) {
            int i = lane*64 + bpos;
            float4 bx = topk[(size_t)b*MROWS + i];
            float* o = out + ((size_t)b*POSTN + rk)*5;
            o[1] = bx.x; o[2] = bx.y; o[3] = bx.z; o[4] = bx.w;
        }
        ++rk;
    }
}

// ---------------- launch ----------------
extern "C" void kernel_launch(void* const* d_in, const int* in_sizes, int n_in,
                              void* d_out, int out_size, void* d_ws, size_t ws_size,
                              hipStream_t stream)
{
    const float* scores  = (const float*)d_in[0];
    const float* deltas  = (const float*)d_in[1];
    const float* im_info = (const float*)d_in[2];
    const float* vrange  = (const float*)d_in[3];
    float* out = (float*)d_out;

    char* ws = (char*)d_ws;
    size_t off = 0;
    auto alloc = [&](size_t bytes) -> void* {
        void* ptr = ws + off;
        off += (bytes + 255) & ~(size_t)255;
        return ptr;
    };
    float4* props  = (float4*)alloc((size_t)NB*NPB*sizeof(float4));      // 9.44 MB
    float* fscores = (float*) alloc((size_t)NB*NPB*sizeof(float));       // 2.36 MB
    u32*   hist    = (u32*)   alloc((size_t)NB*65536*sizeof(u32));       // 1 MB
    u64*   cand    = (u64*)   alloc((size_t)NB*CANDCAP*sizeof(u64));     // 256 KB
    float4* topk   = (float4*)alloc((size_t)NB*MROWS*sizeof(float4));    // 256 KB
    u64*   masks   = (u64*)   alloc((size_t)NB*MROWS*64*sizeof(u64));    // 8.39 MB
    int*   thresh  = (int*)   alloc(64);
    u32*   ccnt    = (u32*)   alloc(64);

    Anchors A;
    gen_anchors(A.v);

    hipMemsetAsync(hist, 0, (size_t)NB*65536*sizeof(u32), stream);
    hipMemsetAsync(ccnt, 0, 64, stream);

    int total = NB*NPB;
    k_props<<<(total + 255)/256, 256, 0, stream>>>(scores, deltas, im_info, vrange,
                                                   A, props, fscores, hist);
    k_findthresh<<<NB, 256, 0, stream>>>(hist, thresh);
    k_compact<<<(total + 255)/256, 256, 0, stream>>>(fscores, thresh, cand, ccnt);
    k_sort<<<NB, 1024, SORTN*sizeof(u64), stream>>>(cand, ccnt, props, topk);
    dim3 mgrid(NTILE, NTILE, NB);
    k_mask<<<mgrid, 64, 0, stream>>>(topk, masks);
    k_fill<<<(NB*POSTN*5 + 255)/256, 256, 0, stream>>>(out);
    k_nms<<<NB, 64, 0, stream>>>(masks, topk, out);
}